// Round 1
// baseline (142.935 us; speedup 1.0000x reference)
//
#include <hip/hip_runtime.h>

// Problem constants
#define G_    5
#define B_    256
#define CO_   24        // C_OTHER
#define CS_   8         // C_SELF (broadcast copies)
#define T_    2048
#define L_    2046      // T - K + 1
#define PLANE_ 6138     // L_*3
#define YPAD_ 6144      // padded y row (16B-aligned, absorbs l=2046,2047 garbage)
#define NGB_  1280      // G_*B_
#define OUTB_ 245520    // 40*PLANE_ : out stride per batch
#define EPS_  1e-5f

// ws layout (float offsets)
#define WS_PSUM_   7864320   // NGB_*YPAD_
#define WS_PSUMSQ_ 7868160   // +15*256
#define WS_SCALE_  7872000   // +15*256
#define WS_SHIFT_  7872015   // +15
// total ~7.87M floats = 31.5 MB

__global__ __launch_bounds__(256) void k_conv(
    const float* __restrict__ x, const float* __restrict__ w,
    const float* __restrict__ bias, float* __restrict__ wsf)
{
    const int gb = blockIdx.x;      // g*256 + b
    const int g  = gb >> 8;
    const int bb = gb & 255;
    const int t  = threadIdx.x;

    __shared__ float sw[216];       // w[g] : (K=3, C=24, K=3)
    if (t < 216) sw[t] = w[g*216 + t];
    __syncthreads();

    const float* xp = x + (size_t)gb * (CO_*T_);
    const int l0 = t << 3;          // 8 l-positions per thread

    float acc[24];                  // [i*3+k], i = l-offset 0..7
    #pragma unroll
    for (int i = 0; i < 24; ++i) acc[i] = 0.f;

    #pragma unroll 2
    for (int c = 0; c < CO_; ++c) {
        const float* xr = xp + c*T_;
        float4 a  = *(const float4*)(xr + l0);
        float4 b4 = *(const float4*)(xr + l0 + 4);
        float4 c4 = make_float4(0.f, 0.f, 0.f, 0.f);
        if (l0 + 11 < T_) c4 = *(const float4*)(xr + l0 + 8);
        float xv[12] = {a.x,a.y,a.z,a.w, b4.x,b4.y,b4.z,b4.w, c4.x,c4.y,c4.z,c4.w};
        #pragma unroll
        for (int k = 0; k < 3; ++k) {
            const float w0 = sw[(k*CO_+c)*3+0];
            const float w1 = sw[(k*CO_+c)*3+1];
            const float w2 = sw[(k*CO_+c)*3+2];
            #pragma unroll
            for (int i = 0; i < 8; ++i)
                acc[i*3+k] += xv[i]*w0 + xv[i+1]*w1 + xv[i+2]*w2;
        }
    }

    const float bk0 = bias[g*3+0], bk1 = bias[g*3+1], bk2 = bias[g*3+2];
    float sum[3] = {0,0,0}, ssq[3] = {0,0,0};
    #pragma unroll
    for (int i = 0; i < 8; ++i) {
        const int l = l0 + i;
        const float v0 = acc[i*3+0] + bk0;
        const float v1 = acc[i*3+1] + bk1;
        const float v2 = acc[i*3+2] + bk2;
        acc[i*3+0] = v0; acc[i*3+1] = v1; acc[i*3+2] = v2;
        if (l < L_) {
            sum[0] += v0; ssq[0] += v0*v0;
            sum[1] += v1; ssq[1] += v1*v1;
            sum[2] += v2; ssq[2] += v2*v2;
        }
    }

    // store y (padded row, garbage beyond l=2045 lands in pad; never read)
    float* yrow = wsf + (size_t)gb * YPAD_;
    #pragma unroll
    for (int i = 0; i < 6; ++i) {
        float4 v = make_float4(acc[i*4+0], acc[i*4+1], acc[i*4+2], acc[i*4+3]);
        *(float4*)(yrow + l0*3 + i*4) = v;
    }

    // block reduction of sum/sumsq (deterministic)
    #pragma unroll
    for (int k = 0; k < 3; ++k) {
        #pragma unroll
        for (int off = 32; off > 0; off >>= 1) {
            sum[k] += __shfl_down(sum[k], off);
            ssq[k] += __shfl_down(ssq[k], off);
        }
    }
    __shared__ float red[4][6];
    const int wid = t >> 6, lane = t & 63;
    if (lane == 0) {
        #pragma unroll
        for (int k = 0; k < 3; ++k) { red[wid][k] = sum[k]; red[wid][3+k] = ssq[k]; }
    }
    __syncthreads();
    if (t == 0) {
        #pragma unroll
        for (int k = 0; k < 3; ++k) {
            float S = red[0][k] + red[1][k] + red[2][k] + red[3][k];
            float Q = red[0][3+k] + red[1][3+k] + red[2][3+k] + red[3][3+k];
            wsf[WS_PSUM_   + (g*3+k)*B_ + bb] = S;
            wsf[WS_PSUMSQ_ + (g*3+k)*B_ + bb] = Q;
        }
    }
}

__global__ __launch_bounds__(256) void k_stats(
    const float* __restrict__ gamma, const float* __restrict__ beta,
    float* __restrict__ wsf)
{
    const int p = blockIdx.x;   // g*3+k, 15 blocks
    const int t = threadIdx.x;
    float S = wsf[WS_PSUM_   + p*B_ + t];
    float Q = wsf[WS_PSUMSQ_ + p*B_ + t];
    #pragma unroll
    for (int off = 32; off > 0; off >>= 1) {
        S += __shfl_down(S, off);
        Q += __shfl_down(Q, off);
    }
    __shared__ float red[4][2];
    const int wid = t >> 6, lane = t & 63;
    if (lane == 0) { red[wid][0] = S; red[wid][1] = Q; }
    __syncthreads();
    if (t == 0) {
        S = red[0][0] + red[1][0] + red[2][0] + red[3][0];
        Q = red[0][1] + red[1][1] + red[2][1] + red[3][1];
        const float invN = 1.f / (float)(B_ * L_);
        const float mu  = S * invN;
        const float var = Q * invN - mu*mu;
        const float rs  = rsqrtf(var + EPS_);
        const float sc  = rs * gamma[p];
        wsf[WS_SCALE_ + p] = sc;
        wsf[WS_SHIFT_ + p] = beta[p] - mu*sc;
    }
}

__global__ __launch_bounds__(256) void k_out(
    const float* __restrict__ wsf, float* __restrict__ out)
{
    const int gb = blockIdx.x;
    const int g  = gb >> 8;
    const int bb = gb & 255;
    const int t  = threadIdx.x;

    const float sc0 = wsf[WS_SCALE_+g*3+0], sc1 = wsf[WS_SCALE_+g*3+1], sc2 = wsf[WS_SCALE_+g*3+2];
    const float sh0 = wsf[WS_SHIFT_+g*3+0], sh1 = wsf[WS_SHIFT_+g*3+1], sh2 = wsf[WS_SHIFT_+g*3+2];

    const float* yrow = wsf + (size_t)gb * YPAD_;
    float* ob = out + (size_t)bb * OUTB_ + (size_t)g * (CS_*PLANE_);

    for (int i = t; i < PLANE_/2; i += 256) {
        const int p0 = 2*i;
        float2 v = *(const float2*)(yrow + p0);
        const int k0 = p0 % 3;
        const int k1 = (k0 == 2) ? 0 : k0 + 1;
        const float a0 = v.x * (k0==0 ? sc0 : (k0==1 ? sc1 : sc2))
                             + (k0==0 ? sh0 : (k0==1 ? sh1 : sh2));
        const float a1 = v.y * (k1==0 ? sc0 : (k1==1 ? sc1 : sc2))
                             + (k1==0 ? sh0 : (k1==1 ? sh1 : sh2));
        float2 s;
        s.x = 1.f / (1.f + __expf(-a0));
        s.y = 1.f / (1.f + __expf(-a1));
        #pragma unroll
        for (int c = 0; c < CS_; ++c)
            *(float2*)(ob + c*PLANE_ + p0) = s;
    }
}

extern "C" void kernel_launch(void* const* d_in, const int* in_sizes, int n_in,
                              void* d_out, int out_size, void* d_ws, size_t ws_size,
                              hipStream_t stream) {
    const float* x_other = (const float*)d_in[0];
    // d_in[1] = x_self: values unused by the reference (only its channel count)
    const float* w     = (const float*)d_in[2];
    const float* b     = (const float*)d_in[3];
    const float* gamma = (const float*)d_in[4];
    const float* beta  = (const float*)d_in[5];
    float* out = (float*)d_out;
    float* wsf = (float*)d_ws;

    hipLaunchKernelGGL(k_conv,  dim3(NGB_), dim3(256), 0, stream, x_other, w, b, wsf);
    hipLaunchKernelGGL(k_stats, dim3(15),   dim3(256), 0, stream, gamma, beta, wsf);
    hipLaunchKernelGGL(k_out,   dim3(NGB_), dim3(256), 0, stream, wsf, out);
}